// Round 3
// baseline (142.736 us; speedup 1.0000x reference)
//
#include <hip/hip_runtime.h>
#include <hip/hip_bf16.h>
#include <cstdint>
#include <cmath>

#define B_ 512
#define T_ 256
#define C_ 256
#define HS_ 64

typedef short bf16x8 __attribute__((ext_vector_type(8)));
typedef float f32x4 __attribute__((ext_vector_type(4)));

static __device__ __forceinline__ unsigned short f2bf(float f) {
    union { float f; unsigned int u; } v; v.f = f;
    unsigned int r = v.u + 0x7fffu + ((v.u >> 16) & 1u);
    return (unsigned short)(r >> 16);
}

// ---- Kernel 0: W -> pre-fragmented bf16 WTf.
// Fragment block fb = (ws*4+f)*8 + kappa (kappa = K-chunk of 32).
// WTf[fb*512 + l*8 + j] = W_ws[k = kappa*32 + (l>>4)*8 + j][n = f*16 + (l&15)]
__global__ void wt_kernel(const float* __restrict__ Wq, const float* __restrict__ Wk,
                          const float* __restrict__ Wv, unsigned short* __restrict__ WTf) {
    int idx = blockIdx.x * 256 + threadIdx.x;     // 6144 total
    if (idx >= 96 * 64) return;
    int fb = idx >> 6;
    int l = idx & 63;
    int ws = fb >> 5;
    int rem = fb & 31;
    int f = rem >> 3;
    int kap = rem & 7;
    const float* W = (ws == 0) ? Wq : ((ws == 1) ? Wk : Wv);
    unsigned short o[8];
#pragma unroll
    for (int j = 0; j < 8; ++j) {
        int k = kap * 32 + (l >> 4) * 8 + j;
        int n = f * 16 + (l & 15);
        o[j] = f2bf(W[k * HS_ + n]);
    }
    *(ulonglong2*)(WTf + (size_t)idx * 8) = *(ulonglong2*)o;
}

// ---- Kernel 1: projection GEMM, global_load_lds staged (fp32 in LDS).
// Block: 256 thr / 4 waves, 128 rows. Wave: 32 rows x 64 cols x 3 mats.
// K processed in 4 quarters of 64; LDS = [128 rows][64 f32] (32 KB), chunk-swizzled.
__global__ __launch_bounds__(256, 3)
void proj_kernel(const float* __restrict__ x, const unsigned short* __restrict__ WTf,
                 unsigned short* __restrict__ Qb, unsigned short* __restrict__ Kb,
                 unsigned short* __restrict__ Vb) {
    __shared__ float xs[8192];     // 32 KB
    const int tid = threadIdx.x;
    const int w = tid >> 6;
    const int l = tid & 63;
    const int ln = l & 15;
    const int lg = l >> 4;
    const int m0 = blockIdx.x * 128;

    f32x4 acc[2][3][4];
#pragma unroll
    for (int t = 0; t < 2; ++t)
#pragma unroll
        for (int a = 0; a < 3; ++a)
#pragma unroll
            for (int f = 0; f < 4; ++f)
                acc[t][a][f] = (f32x4){0.f, 0.f, 0.f, 0.f};

    // stage addressing (issue i: rows i*16 + w*4 + lg, chunk ln swizzled)
    const int srow = w * 4 + lg;                       // row within 16-row slab
    const int sch = ln ^ (srow & 7);                   // pre-swizzled source chunk
    const float* gbase = x + (size_t)(m0 + srow) * C_ + sch * 4;
    float* lbase = &xs[(w * 4) * 64];                  // wave-uniform

    for (int q = 0; q < 4; ++q) {
        // ---- stage quarter q: 8 x global_load_lds dwordx4 per thread-wave ----
#pragma unroll
        for (int i = 0; i < 8; ++i) {
            const float* gp = gbase + q * 64 + (size_t)i * 16 * C_;
            float* lp = lbase + i * 16 * 64;
            __builtin_amdgcn_global_load_lds(
                (const __attribute__((address_space(1))) void*)gp,
                (__attribute__((address_space(3))) void*)lp, 16, 0, 0);
        }
        asm volatile("s_waitcnt vmcnt(0)" ::: "memory");
        __syncthreads();

        // ---- compute quarter q ----
        bf16x8 afr[2][2];      // [kk][t]
#pragma unroll
        for (int kk = 0; kk < 2; ++kk)
#pragma unroll
            for (int t = 0; t < 2; ++t) {
                const int R = w * 32 + t * 16 + ln;
                const int c0 = kk * 8 + lg * 2;
                const int s0 = c0 ^ (R & 7);
                const int s1 = (c0 + 1) ^ (R & 7);
                f32x4 fa = *(const f32x4*)&xs[R * 64 + s0 * 4];   // floats j=0..3
                f32x4 fb = *(const f32x4*)&xs[R * 64 + s1 * 4];   // floats j=4..7
                bf16x8 a;
                a[0] = f2bf(fa[0]); a[1] = f2bf(fa[1]); a[2] = f2bf(fa[2]); a[3] = f2bf(fa[3]);
                a[4] = f2bf(fb[0]); a[5] = f2bf(fb[1]); a[6] = f2bf(fb[2]); a[7] = f2bf(fb[3]);
                afr[kk][t] = a;
            }
#pragma unroll
        for (int kk = 0; kk < 2; ++kk) {
            const int kap = q * 2 + kk;
#pragma unroll
            for (int ws_ = 0; ws_ < 3; ++ws_)
#pragma unroll
                for (int f = 0; f < 4; ++f) {
                    bf16x8 bfr = *(const bf16x8*)(WTf
                        + ((size_t)((ws_ * 4 + f) * 8 + kap) * 64 + l) * 8);
#pragma unroll
                    for (int t = 0; t < 2; ++t)
                        acc[t][ws_][f] = __builtin_amdgcn_mfma_f32_16x16x32_bf16(
                            bfr, afr[kk][t], acc[t][ws_][f], 0, 0, 0);
                }
        }
        __syncthreads();   // all reads done before next quarter's stage
    }

    // ---- store: lane holds out[row=ln][cols f*16+lg*4 .. +3] -> ushort4 ----
    unsigned short* dsts[3] = {Qb, Kb, Vb};
#pragma unroll
    for (int t = 0; t < 2; ++t)
#pragma unroll
        for (int ws_ = 0; ws_ < 3; ++ws_)
#pragma unroll
            for (int f = 0; f < 4; ++f) {
                const int row = m0 + w * 32 + t * 16 + ln;
                ushort4 o;
                o.x = f2bf(acc[t][ws_][f][0]);
                o.y = f2bf(acc[t][ws_][f][1]);
                o.z = f2bf(acc[t][ws_][f][2]);
                o.w = f2bf(acc[t][ws_][f][3]);
                *(ushort4*)(dsts[ws_] + (size_t)row * HS_ + f * 16 + lg * 4) = o;
            }
}

// ---- Kernel 2: flash-style causal attention (unchanged) ----
__global__ __launch_bounds__(256)
void attn_kernel(const unsigned short* __restrict__ Qb, const unsigned short* __restrict__ Kb,
                 const unsigned short* __restrict__ Vb, float* __restrict__ out) {
    __shared__ unsigned short P_lds[4][16][40];

    const int w = threadIdx.x >> 6;
    const int l = threadIdx.x & 63;
    const int ln = l & 15;
    const int lg = l >> 4;
    const int b = blockIdx.x >> 2;
    const int qt = blockIdx.x & 3;
    const int q0 = qt * 64;
    const int r0 = q0 + w * 16;
    const size_t base = (size_t)b * T_ * HS_;
    const float scale = 0.0625f;

    bf16x8 qa[2];
#pragma unroll
    for (int kk = 0; kk < 2; ++kk)
        qa[kk] = *(const bf16x8*)(Qb + base + (size_t)(r0 + ln) * HS_ + kk * 32 + lg * 8);

    float m[4], lsum[4];
    f32x4 o[4];
#pragma unroll
    for (int r = 0; r < 4; ++r) { m[r] = -INFINITY; lsum[r] = 0.f; }
#pragma unroll
    for (int f = 0; f < 4; ++f) o[f] = (f32x4){0.f, 0.f, 0.f, 0.f};

    const int nkt = qt * 2 + 2;
    for (int kt = 0; kt < nkt; ++kt) {
        const int n0 = kt * 32;

        f32x4 s[2];
#pragma unroll
        for (int h = 0; h < 2; ++h) {
            bf16x8 kb0 = *(const bf16x8*)(Kb + base + (size_t)(n0 + 16 * h + ln) * HS_ + lg * 8);
            bf16x8 kb1 = *(const bf16x8*)(Kb + base + (size_t)(n0 + 16 * h + ln) * HS_ + 32 + lg * 8);
            f32x4 z = (f32x4){0.f, 0.f, 0.f, 0.f};
            z = __builtin_amdgcn_mfma_f32_16x16x32_bf16(qa[0], kb0, z, 0, 0, 0);
            s[h] = __builtin_amdgcn_mfma_f32_16x16x32_bf16(qa[1], kb1, z, 0, 0, 0);
        }

        float sm[2][4];
#pragma unroll
        for (int r = 0; r < 4; ++r) {
            const int qrow = r0 + lg * 4 + r;
#pragma unroll
            for (int h = 0; h < 2; ++h) {
                float v = s[h][r] * scale;
                sm[h][r] = (qrow >= n0 + 16 * h + ln) ? v : -INFINITY;
            }
        }

        float fac[4], p[2][4];
#pragma unroll
        for (int r = 0; r < 4; ++r) {
            float tmax = fmaxf(sm[0][r], sm[1][r]);
#pragma unroll
            for (int mask = 1; mask < 16; mask <<= 1)
                tmax = fmaxf(tmax, __shfl_xor(tmax, mask, 64));
            float mn = fmaxf(m[r], tmax);
            fac[r] = __expf(m[r] - mn);
            p[0][r] = __expf(sm[0][r] - mn);
            p[1][r] = __expf(sm[1][r] - mn);
            float rs = p[0][r] + p[1][r];
#pragma unroll
            for (int mask = 1; mask < 16; mask <<= 1)
                rs += __shfl_xor(rs, mask, 64);
            lsum[r] = lsum[r] * fac[r] + rs;
            m[r] = mn;
        }
#pragma unroll
        for (int f = 0; f < 4; ++f)
#pragma unroll
            for (int r = 0; r < 4; ++r)
                o[f][r] *= fac[r];

#pragma unroll
        for (int h = 0; h < 2; ++h)
#pragma unroll
            for (int r = 0; r < 4; ++r)
                P_lds[w][lg * 4 + r][16 * h + ln] = f2bf(p[h][r]);

        bf16x8 pa = *(const bf16x8*)(&P_lds[w][ln][lg * 8]);

#pragma unroll
        for (int f = 0; f < 4; ++f) {
            bf16x8 vb;
#pragma unroll
            for (int j = 0; j < 8; ++j)
                vb[j] = (short)Vb[base + (size_t)(n0 + lg * 8 + j) * HS_ + 16 * f + ln];
            o[f] = __builtin_amdgcn_mfma_f32_16x16x32_bf16(pa, vb, o[f], 0, 0, 0);
        }
    }

#pragma unroll
    for (int f = 0; f < 4; ++f)
#pragma unroll
        for (int r = 0; r < 4; ++r) {
            int trow = r0 + lg * 4 + r;
            out[base + (size_t)trow * HS_ + 16 * f + ln] = o[f][r] / lsum[r];
        }
}

extern "C" void kernel_launch(void* const* d_in, const int* in_sizes, int n_in,
                              void* d_out, int out_size, void* d_ws, size_t ws_size,
                              hipStream_t stream) {
    const float* x  = (const float*)d_in[0];
    const float* Wq = (const float*)d_in[1];
    const float* Wk = (const float*)d_in[2];
    const float* Wv = (const float*)d_in[3];
    float* out = (float*)d_out;

    unsigned short* WTf = (unsigned short*)d_ws;                // 96*64*8 = 49152
    unsigned short* Qb = WTf + 96 * 64 * 8;
    unsigned short* Kb = Qb + (size_t)B_ * T_ * HS_;
    unsigned short* Vb = Kb + (size_t)B_ * T_ * HS_;

    wt_kernel<<<24, 256, 0, stream>>>(Wq, Wk, Wv, WTf);
    proj_kernel<<<(B_ * T_) / 128, 256, 0, stream>>>(x, WTf, Qb, Kb, Vb);
    attn_kernel<<<B_ * 4, 256, 0, stream>>>(Qb, Kb, Vb, out);
}

// Round 4
// 127.477 us; speedup vs baseline: 1.1197x; 1.1197x over previous
//
#include <hip/hip_runtime.h>
#include <hip/hip_bf16.h>
#include <cstdint>
#include <cmath>

#define B_ 512
#define T_ 256
#define C_ 256
#define HS_ 64

typedef short bf16x8 __attribute__((ext_vector_type(8)));
typedef float f32x4 __attribute__((ext_vector_type(4)));

static __device__ __forceinline__ unsigned short f2bf(float f) {
    union { float f; unsigned int u; } v; v.f = f;
    unsigned int r = v.u + 0x7fffu + ((v.u >> 16) & 1u);
    return (unsigned short)(r >> 16);
}

// ---- Kernel 0: W -> pre-fragmented bf16 WTf.
// fb = (ws*4+f)*8 + kap ; WTf[fb*512 + l*8 + j] = W_ws[kap*32 + (l>>4)*8 + j][f*16 + (l&15)]
__global__ void wt_kernel(const float* __restrict__ Wq, const float* __restrict__ Wk,
                          const float* __restrict__ Wv, unsigned short* __restrict__ WTf) {
    int idx = blockIdx.x * 256 + threadIdx.x;     // 6144 total
    if (idx >= 96 * 64) return;
    int fb = idx >> 6;
    int l = idx & 63;
    int ws = fb >> 5;
    int rem = fb & 31;
    int f = rem >> 3;
    int kap = rem & 7;
    const float* W = (ws == 0) ? Wq : ((ws == 1) ? Wk : Wv);
    unsigned short o[8];
#pragma unroll
    for (int j = 0; j < 8; ++j) {
        int k = kap * 32 + (l >> 4) * 8 + j;
        int n = f * 16 + (l & 15);
        o[j] = f2bf(W[k * HS_ + n]);
    }
    *(ulonglong2*)(WTf + (size_t)idx * 8) = *(ulonglong2*)o;
}

#define WAITV(N) asm volatile("s_waitcnt vmcnt(" #N ")" ::: "memory")

// stage quarter Q of this wave's 32 rows into buf (Q&1): 8 x global_load_lds(16B)
#define STAGE(Q) do { \
    float* lbase_ = xs + ((Q) & 1) * 8192 + w * 2048; \
    _Pragma("unroll") \
    for (int i_ = 0; i_ < 8; ++i_) { \
        const int r_ = i_ * 4 + lg; \
        const float* gp_ = x + (size_t)(m0 + w * 32 + r_) * C_ \
                           + ((ln ^ (r_ & 7)) * 4 + (Q) * 64); \
        __builtin_amdgcn_global_load_lds( \
            (const __attribute__((address_space(1))) void*)gp_, \
            (__attribute__((address_space(3))) void*)(lbase_ + i_ * 256), 16, 0, 0); \
    } \
} while (0)

// load the 12 W-fragments of K-chunk KAP into breg[P]
#define BLOAD(P, KAP) do { \
    _Pragma("unroll") \
    for (int j_ = 0; j_ < 12; ++j_) \
        breg[P][j_] = *(const bf16x8*)(WTf + ((size_t)(j_ * 8 + (KAP)) * 64 + l) * 8); \
} while (0)

// ---- Kernel 1: projection GEMM, barrier-free counted-vmcnt pipeline.
// Block: 256 thr / 4 waves, 128 rows; wave owns 32 rows (fully independent in K-loop).
__global__ __launch_bounds__(256, 2)
void proj_kernel(const float* __restrict__ x, const unsigned short* __restrict__ WTf,
                 unsigned short* __restrict__ Qb, unsigned short* __restrict__ Kb,
                 unsigned short* __restrict__ Vt) {
    __shared__ float xs[16384];    // 64 KB: 2 x 32 KB quarter buffers (reused as epilogue bounce)
    const int tid = threadIdx.x;
    const int w = tid >> 6;
    const int l = tid & 63;
    const int ln = l & 15;
    const int lg = l >> 4;
    const int m0 = blockIdx.x * 128;

    f32x4 acc[2][3][4];
#pragma unroll
    for (int t = 0; t < 2; ++t)
#pragma unroll
        for (int a = 0; a < 3; ++a)
#pragma unroll
            for (int f = 0; f < 4; ++f)
                acc[t][a][f] = (f32x4){0.f, 0.f, 0.f, 0.f};

    bf16x8 breg[2][12];

    // preamble: S0 B0 S1 B1  (outstanding vmem = 8+12+8+12 = 40)
    STAGE(0);
    __builtin_amdgcn_sched_barrier(0);
    BLOAD(0, 0);
    __builtin_amdgcn_sched_barrier(0);
    STAGE(1);
    __builtin_amdgcn_sched_barrier(0);
    BLOAD(1, 1);

#pragma unroll
    for (int kap = 0; kap < 8; ++kap) {
        __builtin_amdgcn_sched_barrier(0);
        // wait ladder: {20,12,20,12,20,12,12,0}
        if (kap == 0 || kap == 2 || kap == 4) WAITV(20);
        else if (kap == 7) WAITV(0);
        else WAITV(12);
        __builtin_amdgcn_sched_barrier(0);

        // ---- compute K-chunk kap ----
        bf16x8 afr[2];
        const int p = (kap >> 1) & 1;
#pragma unroll
        for (int t = 0; t < 2; ++t) {
            const int R = t * 16 + ln;
            const int base = p * 8192 + w * 2048 + R * 64;
            const int c0 = (kap & 1) * 8 + lg * 2;
            f32x4 fa  = *(const f32x4*)&xs[base + ((c0 ^ (R & 7)) * 4)];
            f32x4 fb2 = *(const f32x4*)&xs[base + (((c0 + 1) ^ (R & 7)) * 4)];
            bf16x8 a;
            a[0] = f2bf(fa[0]);  a[1] = f2bf(fa[1]);  a[2] = f2bf(fa[2]);  a[3] = f2bf(fa[3]);
            a[4] = f2bf(fb2[0]); a[5] = f2bf(fb2[1]); a[6] = f2bf(fb2[2]); a[7] = f2bf(fb2[3]);
            afr[t] = a;
        }
#pragma unroll
        for (int ws_ = 0; ws_ < 3; ++ws_)
#pragma unroll
            for (int f = 0; f < 4; ++f)
#pragma unroll
                for (int t = 0; t < 2; ++t)
                    acc[t][ws_][f] = __builtin_amdgcn_mfma_f32_16x16x32_bf16(
                        breg[kap & 1][ws_ * 4 + f], afr[t], acc[t][ws_][f], 0, 0, 0);
        __builtin_amdgcn_sched_barrier(0);

        // ---- prefetch issues ----
        if (kap == 0) { BLOAD(0, 2); }
        if (kap == 1) { asm volatile("s_waitcnt lgkmcnt(0)" ::: "memory"); STAGE(2); BLOAD(1, 3); }
        if (kap == 2) { BLOAD(0, 4); }
        if (kap == 3) { asm volatile("s_waitcnt lgkmcnt(0)" ::: "memory"); STAGE(3); BLOAD(1, 5); }
        if (kap == 4) { BLOAD(0, 6); }
        if (kap == 5) { BLOAD(1, 7); }
    }

    // ================= epilogue: LDS bounce -> coalesced stores =================
    __syncthreads();
    unsigned short* bs = (unsigned short*)xs;

    // bounce Q,K row-major [0,32K), V transposed [32K,48K); all XOR-swizzled
#pragma unroll
    for (int t = 0; t < 2; ++t)
#pragma unroll
        for (int ws_ = 0; ws_ < 2; ++ws_)
#pragma unroll
            for (int f = 0; f < 4; ++f) {
                const int rl = w * 32 + t * 16 + ln;
                ushort4 o;
                o.x = f2bf(acc[t][ws_][f][0]);
                o.y = f2bf(acc[t][ws_][f][1]);
                o.z = f2bf(acc[t][ws_][f][2]);
                o.w = f2bf(acc[t][ws_][f][3]);
                char* dst = (char*)bs + ws_ * 16384 + rl * 128
                            + ((f * 32 + lg * 8) ^ ((rl & 7) << 4));
                *(ushort4*)dst = o;
            }
#pragma unroll
    for (int t = 0; t < 2; ++t)
#pragma unroll
        for (int f = 0; f < 4; ++f)
#pragma unroll
            for (int i = 0; i < 4; ++i) {
                const int rl = w * 32 + t * 16 + ln;
                const int col = f * 16 + lg * 4 + i;
                char* dst = (char*)bs + 32768 + col * 256
                            + ((rl * 2) ^ ((col & 7) << 4));
                *(unsigned short*)dst = f2bf(acc[t][2][f][i]);
            }
    __syncthreads();

    // coalesced stores: Q,K row-major
#pragma unroll
    for (int ws_ = 0; ws_ < 2; ++ws_) {
        unsigned short* gdst = (ws_ == 0 ? Qb : Kb) + (size_t)m0 * 64;
#pragma unroll
        for (int pp = 0; pp < 4; ++pp) {
            int idx = pp * 256 + tid;                 // 16B chunk id, 0..1023
            int row = idx >> 3, u = idx & 7;
            const char* srcp = (const char*)bs + ws_ * 16384 + row * 128
                               + ((u << 4) ^ ((row & 7) << 4));
            ulonglong2 v = *(const ulonglong2*)srcp;
            *(ulonglong2*)(gdst + (size_t)idx * 8) = v;
        }
    }
    // V transposed: Vt[batch][col 0..63][trow 0..255]
    {
        const int bb = m0 >> 8, ro = m0 & 255;
        unsigned short* gdst = Vt + (size_t)bb * 16384;
#pragma unroll
        for (int pp = 0; pp < 4; ++pp) {
            int idx = pp * 256 + tid;                 // 0..1023; col=idx>>4, u=idx&15
            int col = idx >> 4, u = idx & 15;
            const char* srcp = (const char*)bs + 32768 + col * 256
                               + ((u << 4) ^ ((col & 7) << 4));
            ulonglong2 v = *(const ulonglong2*)srcp;
            *(ulonglong2*)(gdst + (size_t)col * 256 + ro + u * 8) = v;
        }
    }
}

// ---- Kernel 2: flash-style causal attention (V now pre-transposed) ----
__global__ __launch_bounds__(256)
void attn_kernel(const unsigned short* __restrict__ Qb, const unsigned short* __restrict__ Kb,
                 const unsigned short* __restrict__ Vt, float* __restrict__ out) {
    __shared__ unsigned short P_lds[4][16][40];

    const int w = threadIdx.x >> 6;
    const int l = threadIdx.x & 63;
    const int ln = l & 15;
    const int lg = l >> 4;
    const int b = blockIdx.x >> 2;
    const int qt = blockIdx.x & 3;
    const int q0 = qt * 64;
    const int r0 = q0 + w * 16;
    const size_t base = (size_t)b * T_ * HS_;
    const size_t vbase = (size_t)b * HS_ * T_;       // Vt: [64][256] per batch
    const float scale = 0.0625f;

    bf16x8 qa[2];
#pragma unroll
    for (int kk = 0; kk < 2; ++kk)
        qa[kk] = *(const bf16x8*)(Qb + base + (size_t)(r0 + ln) * HS_ + kk * 32 + lg * 8);

    float m[4], lsum[4];
    f32x4 o[4];
#pragma unroll
    for (int r = 0; r < 4; ++r) { m[r] = -INFINITY; lsum[r] = 0.f; }
#pragma unroll
    for (int f = 0; f < 4; ++f) o[f] = (f32x4){0.f, 0.f, 0.f, 0.f};

    const int nkt = qt * 2 + 2;
    for (int kt = 0; kt < nkt; ++kt) {
        const int n0 = kt * 32;

        f32x4 s[2];
#pragma unroll
        for (int h = 0; h < 2; ++h) {
            bf16x8 kb0 = *(const bf16x8*)(Kb + base + (size_t)(n0 + 16 * h + ln) * HS_ + lg * 8);
            bf16x8 kb1 = *(const bf16x8*)(Kb + base + (size_t)(n0 + 16 * h + ln) * HS_ + 32 + lg * 8);
            f32x4 z = (f32x4){0.f, 0.f, 0.f, 0.f};
            z = __builtin_amdgcn_mfma_f32_16x16x32_bf16(qa[0], kb0, z, 0, 0, 0);
            s[h] = __builtin_amdgcn_mfma_f32_16x16x32_bf16(qa[1], kb1, z, 0, 0, 0);
        }

        float sm[2][4];
#pragma unroll
        for (int r = 0; r < 4; ++r) {
            const int qrow = r0 + lg * 4 + r;
#pragma unroll
            for (int h = 0; h < 2; ++h) {
                float v = s[h][r] * scale;
                sm[h][r] = (qrow >= n0 + 16 * h + ln) ? v : -INFINITY;
            }
        }

        float fac[4], p[2][4];
#pragma unroll
        for (int r = 0; r < 4; ++r) {
            float tmax = fmaxf(sm[0][r], sm[1][r]);
#pragma unroll
            for (int mask = 1; mask < 16; mask <<= 1)
                tmax = fmaxf(tmax, __shfl_xor(tmax, mask, 64));
            float mn = fmaxf(m[r], tmax);
            fac[r] = __expf(m[r] - mn);
            p[0][r] = __expf(sm[0][r] - mn);
            p[1][r] = __expf(sm[1][r] - mn);
            float rs = p[0][r] + p[1][r];
#pragma unroll
            for (int mask = 1; mask < 16; mask <<= 1)
                rs += __shfl_xor(rs, mask, 64);
            lsum[r] = lsum[r] * fac[r] + rs;
            m[r] = mn;
        }
#pragma unroll
        for (int f = 0; f < 4; ++f)
#pragma unroll
            for (int r = 0; r < 4; ++r)
                o[f][r] *= fac[r];

#pragma unroll
        for (int h = 0; h < 2; ++h)
#pragma unroll
            for (int r = 0; r < 4; ++r)
                P_lds[w][lg * 4 + r][16 * h + ln] = f2bf(p[h][r]);

        bf16x8 pa = *(const bf16x8*)(&P_lds[w][ln][lg * 8]);

        // PV: V^T gives contiguous 16B B-fragments
#pragma unroll
        for (int f = 0; f < 4; ++f) {
            bf16x8 vb = *(const bf16x8*)(Vt + vbase + (size_t)(f * 16 + ln) * T_ + n0 + lg * 8);
            o[f] = __builtin_amdgcn_mfma_f32_16x16x32_bf16(pa, vb, o[f], 0, 0, 0);
        }
    }

#pragma unroll
    for (int f = 0; f < 4; ++f)
#pragma unroll
        for (int r = 0; r < 4; ++r) {
            int trow = r0 + lg * 4 + r;
            out[base + (size_t)trow * HS_ + 16 * f + ln] = o[f][r] / lsum[r];
        }
}

extern "C" void kernel_launch(void* const* d_in, const int* in_sizes, int n_in,
                              void* d_out, int out_size, void* d_ws, size_t ws_size,
                              hipStream_t stream) {
    const float* x  = (const float*)d_in[0];
    const float* Wq = (const float*)d_in[1];
    const float* Wk = (const float*)d_in[2];
    const float* Wv = (const float*)d_in[3];
    float* out = (float*)d_out;

    unsigned short* WTf = (unsigned short*)d_ws;                // 96 KB
    unsigned short* Qb = WTf + 96 * 64 * 8;
    unsigned short* Kb = Qb + (size_t)B_ * T_ * HS_;
    unsigned short* Vt = Kb + (size_t)B_ * T_ * HS_;

    wt_kernel<<<24, 256, 0, stream>>>(Wq, Wk, Wv, WTf);
    proj_kernel<<<(B_ * T_) / 128, 256, 0, stream>>>(x, WTf, Qb, Kb, Vt);
    attn_kernel<<<B_ * 4, 256, 0, stream>>>(Qb, Kb, Vt, out);
}